// Round 9
// baseline (523.112 us; speedup 1.0000x reference)
//
#include <hip/hip_runtime.h>

typedef _Float16 half_t;
typedef __attribute__((ext_vector_type(8))) _Float16 f16x8;
typedef __attribute__((ext_vector_type(4))) float f32x4;

#define DM 256
#define NH 8
#define NN 256
#define NB 2
#define JT 32

// ---- prep: transposed f16 weights: WT[c][k]=W[k][c]; W1T[m][k]=W1[k][m];
// ---- W2T[n][k]=W2[k][n]. grid 1536.
__global__ __launch_bounds__(256) void k_prep(const float* __restrict__ W,
                                              const float* __restrict__ W1,
                                              const float* __restrict__ W2,
                                              half_t* __restrict__ WT,
                                              half_t* __restrict__ W1T,
                                              half_t* __restrict__ W2T) {
  const int t = threadIdx.x, bid = blockIdx.x;
  if (bid < 256) {
    WT[bid * 256 + t] = (half_t)W[(size_t)t * 256 + bid];
  } else if (bid < 1280) {
    int m = bid - 256;
    W1T[(size_t)m * 256 + t] = (half_t)W1[(size_t)t * 1024 + m];
  } else {
    int n = bid - 1280;
#pragma unroll
    for (int j = 0; j < 4; ++j) {
      int k = j * 256 + t;
      W2T[(size_t)n * 1024 + k] = (half_t)W2[(size_t)k * 256 + n];
    }
  }
}

// ---- fused LN + node proj: xs = LN(nodes); nqv = xs@W + b; nqvpb = nqv + b -
__global__ __launch_bounds__(1024) void k_ln_proj(
    const float* __restrict__ nodes, const half_t* __restrict__ WT,
    const float* __restrict__ bias, const float* __restrict__ ln_g,
    const float* __restrict__ ln_b, float* __restrict__ xs,
    float* __restrict__ nqv, float* __restrict__ nqvpb) {
  __shared__ float sx[2][DM];
  __shared__ float pp[4][2][DM];
  __shared__ float rs[8], rq[8];
  const int t = threadIdx.x;
  const int r0 = blockIdx.x * 2;
  const int row = t >> 8, col = t & 255;
  float v = 0.f;
  if (t < 512) v = nodes[(size_t)(r0 + row) * DM + col];
  float s = v, q = v * v;
#pragma unroll
  for (int m = 1; m <= 32; m <<= 1) {
    s += __shfl_xor(s, m, 64);
    q += __shfl_xor(q, m, 64);
  }
  if (t < 512 && (t & 63) == 0) { rs[t >> 6] = s; rq[t >> 6] = q; }
  __syncthreads();
  if (t < 512) {
    int rb = row * 4;
    float ss = rs[rb] + rs[rb + 1] + rs[rb + 2] + rs[rb + 3];
    float qq = rq[rb] + rq[rb + 1] + rq[rb + 2] + rq[rb + 3];
    float mu = ss * (1.f / DM);
    float var = qq * (1.f / DM) - mu * mu;
    float xv = (v - mu) * rsqrtf(var + 1e-5f) * ln_g[col] + ln_b[col];
    sx[row][col] = xv;
    xs[(size_t)(r0 + row) * DM + col] = xv;
  }
  __syncthreads();
  const int rg = t >> 8;
  float a0 = 0.f, a1 = 0.f;
#pragma unroll
  for (int k8 = 0; k8 < 8; ++k8) {
    int k = rg * 64 + k8 * 8;
    f16x8 wv = *(const f16x8*)(WT + (size_t)col * 256 + k);
    f32x4 xa0 = *(const f32x4*)(&sx[0][k]);
    f32x4 xb0 = *(const f32x4*)(&sx[0][k + 4]);
    f32x4 xa1 = *(const f32x4*)(&sx[1][k]);
    f32x4 xb1 = *(const f32x4*)(&sx[1][k + 4]);
#pragma unroll
    for (int z = 0; z < 4; ++z) {
      a0 += xa0[z] * (float)wv[z];
      a0 += xb0[z] * (float)wv[z + 4];
      a1 += xa1[z] * (float)wv[z];
      a1 += xb1[z] * (float)wv[z + 4];
    }
  }
  pp[rg][0][col] = a0;
  pp[rg][1][col] = a1;
  __syncthreads();
  if (t < 512) {
    float bb = bias[col];
    float r = pp[0][row][col] + pp[1][row][col] + pp[2][row][col] +
              pp[3][row][col] + bb;
    nqv[(size_t)(r0 + row) * DM + col] = r;
    nqvpb[(size_t)(r0 + row) * DM + col] = r + bb;
  }
}

// ---------------- fused edge proj + scores ---------------------------------
// EP = edge[b,i,j0:j0+32,:] @ W (f16 MFMA, f32 accum, swapped: D[c,j])
// score[h,j] = 10*tanh( (1/sqrt32) * sum_{c in h} (EP+qi_c)(EP+kj_c) )
// ALL edge chunks prefetched at entry -> no exposed HBM latency in k-loop.
__global__ __launch_bounds__(256, 4) void k_edge_scores(
    const float* __restrict__ edges, const half_t* __restrict__ WT,
    const float* __restrict__ nqvpb, float* __restrict__ scores) {
  __shared__ __align__(16) char smem[4096 + 32 * 1040];
  const int tid = threadIdx.x;
  const int l = tid & 63;
  const int w = tid >> 6;
  const int idx = blockIdx.x;
  const int jb = idx & 7;
  const int i = (idx >> 3) & (NN - 1);
  const int b = idx >> 11;
  const int j0 = jb * JT;

  const float* eg = edges + ((size_t)(b * NN + i) * NN + j0) * DM;
  const int f4 = tid & 15, row0 = tid >> 4;

  // prefetch ALL edge chunks at entry: 8 dwordx4 in flight immediately
  f32x4 pe[4][2];
#pragma unroll
  for (int kc = 0; kc < 4; ++kc) {
    pe[kc][0] = *(const f32x4*)(eg + row0 * DM + kc * 64 + f4 * 4);
    pe[kc][1] = *(const f32x4*)(eg + (row0 + 16) * DM + kc * 64 + f4 * 4);
  }

  float* nlds = (float*)(smem + 4096);  // 32 rows, stride 260 floats
  const float* nb_ = nqvpb + ((size_t)(b * NN) + j0) * DM;
#pragma unroll
  for (int p = 0; p < 8; ++p) {
    int u = p * 256 + tid;
    int row = u >> 6, c4 = u & 63;
    f32x4 v = *(const f32x4*)(nb_ + (size_t)row * DM + c4 * 4);
    *(f32x4*)(nlds + row * 260 + c4 * 4) = v;
  }

  f32x4 acc[4][2];
#pragma unroll
  for (int ct = 0; ct < 4; ++ct)
#pragma unroll
    for (int jt = 0; jt < 2; ++jt) acc[ct][jt] = (f32x4){0.f, 0.f, 0.f, 0.f};

  const char* wtb = (const char*)WT;

#pragma unroll
  for (int kc = 0; kc < 4; ++kc) {
    // WT fragments (L2-hot), issued before convert+barrier
    f16x8 wf[2][4];
#pragma unroll
    for (int ks = 0; ks < 2; ++ks)
#pragma unroll
      for (int ct = 0; ct < 4; ++ct) {
        int c = w * 64 + ct * 16 + (l & 15);
        wf[ks][ct] = *(const f16x8*)(wtb + c * 512 + kc * 128 + ks * 64 +
                                     ((l >> 4) * 16));
      }
    // convert prefetched regs + swizzled LDS write of A (edge tile)
#pragma unroll
    for (int q = 0; q < 2; ++q) {
      int row = row0 + q * 16;
      union { unsigned long long u; half_t h[4]; } a1;
#pragma unroll
      for (int z = 0; z < 4; ++z) a1.h[z] = (half_t)pe[kc][q][z];
      int off = (row * 128 + f4 * 8) ^ ((row & 7) << 4);
      *(unsigned long long*)(smem + off) = a1.u;
    }
    __syncthreads();
#pragma unroll
    for (int ks = 0; ks < 2; ++ks) {
      f16x8 fq[2];
#pragma unroll
      for (int jt = 0; jt < 2; ++jt) {
        int r = jt * 16 + (l & 15);
        int off = (r * 128 + ks * 64 + ((l >> 4) * 16)) ^ ((r & 7) << 4);
        fq[jt] = *(const f16x8*)(smem + off);
      }
#pragma unroll
      for (int ct = 0; ct < 4; ++ct)
#pragma unroll
        for (int jt = 0; jt < 2; ++jt)
          acc[ct][jt] = __builtin_amdgcn_mfma_f32_16x16x32_f16(
              wf[ks][ct], fq[jt], acc[ct][jt], 0, 0, 0);
    }
    __syncthreads();
  }

  // epilogue: score = sum_c (EP+qi)(EP+kj)
  const float* qrow = nqvpb + ((size_t)(b * NN) + i) * DM;
  const float scale = 0.17677669529663687f;  // 1/sqrt(32)
#pragma unroll
  for (int a = 0; a < 2; ++a) {
    float s0 = 0.f, s1 = 0.f;
#pragma unroll
    for (int u = 0; u < 2; ++u) {
      int ct = a * 2 + u;
      int cbase = w * 64 + ct * 16 + ((l >> 4) * 4);
      f32x4 qi = *(const f32x4*)(qrow + cbase);
      f32x4 k0 = *(const f32x4*)(nlds + (l & 15) * 260 + cbase);
      f32x4 k1 = *(const f32x4*)(nlds + (16 + (l & 15)) * 260 + cbase);
#pragma unroll
      for (int rr = 0; rr < 4; ++rr) {
        s0 += (acc[ct][0][rr] + qi[rr]) * (acc[ct][0][rr] + k0[rr]);
        s1 += (acc[ct][1][rr] + qi[rr]) * (acc[ct][1][rr] + k1[rr]);
      }
    }
#pragma unroll
    for (int jt = 0; jt < 2; ++jt) {
      float sv = jt ? s1 : s0;
      sv += __shfl_xor(sv, 16, 64);
      sv += __shfl_xor(sv, 32, 64);
      float sc = 10.0f * tanhf(sv * scale);
      if (l < 16) {
        int h = w * 2 + a;
        int jg = j0 + jt * 16 + l;
        scores[(((size_t)(b * NH) + h) * NN + i) * NN + jg] = sc;
      }
    }
  }
}

// ---- fused softmax + attn@V + out-proj + residual + LN --------------------
__global__ __launch_bounds__(1024) void k_attn_out(
    const float* __restrict__ scores, const float* __restrict__ nqv,
    const half_t* __restrict__ WT, const float* __restrict__ bias,
    const float* __restrict__ xs, const float* __restrict__ ln_g,
    const float* __restrict__ ln_b, float* __restrict__ ys) {
  __shared__ float sp[NH * NN];
  __shared__ float pp[4][256];
  __shared__ float aor[256];
  __shared__ float rs[4], rq[4];
  const int t = threadIdx.x;
  const int b = blockIdx.x >> 8, i = blockIdx.x & 255;
#pragma unroll
  for (int p = 0; p < 2; ++p) {
    int idx2 = p * 1024 + t;
    sp[idx2] = scores[(((size_t)(b * NH) + (idx2 >> 8)) * NN + i) * NN + (idx2 & 255)];
  }
  __syncthreads();
  const int w = t >> 6, l = t & 63;
  if (w < 8) {
    f32x4 v = *(f32x4*)(sp + w * NN + l * 4);
    float m = fmaxf(fmaxf(v[0], v[1]), fmaxf(v[2], v[3]));
#pragma unroll
    for (int mm = 1; mm <= 32; mm <<= 1) m = fmaxf(m, __shfl_xor(m, mm, 64));
    v[0] = __expf(v[0] - m); v[1] = __expf(v[1] - m);
    v[2] = __expf(v[2] - m); v[3] = __expf(v[3] - m);
    float s = v[0] + v[1] + v[2] + v[3];
#pragma unroll
    for (int mm = 1; mm <= 32; mm <<= 1) s += __shfl_xor(s, mm, 64);
    float inv = 1.0f / s;
    v[0] *= inv; v[1] *= inv; v[2] *= inv; v[3] *= inv;
    *(f32x4*)(sp + w * NN + l * 4) = v;
  }
  __syncthreads();
  const int d = t & 255, kg = t >> 8, h = d >> 5;
  const float* vb = nqv + (size_t)b * NN * DM;
  float acc = 0.f;
#pragma unroll 8
  for (int jj = 0; jj < 64; ++jj) {
    int j = kg * 64 + jj;
    acc += sp[h * 256 + j] * vb[(size_t)j * DM + d];
  }
  pp[kg][d] = acc;
  __syncthreads();
  if (t < 256) aor[t] = pp[0][t] + pp[1][t] + pp[2][t] + pp[3][t];
  __syncthreads();
  float a0 = 0.f;
#pragma unroll
  for (int k8 = 0; k8 < 8; ++k8) {
    int k = kg * 64 + k8 * 8;
    f16x8 wv = *(const f16x8*)(WT + (size_t)d * 256 + k);
    f32x4 ya = *(const f32x4*)(&aor[k]);
    f32x4 yb = *(const f32x4*)(&aor[k + 4]);
#pragma unroll
    for (int z = 0; z < 4; ++z)
      a0 += ya[z] * (float)wv[z] + yb[z] * (float)wv[z + 4];
  }
  pp[kg][d] = a0;
  __syncthreads();
  float val = 0.f;
  if (t < 256)
    val = pp[0][t] + pp[1][t] + pp[2][t] + pp[3][t] + bias[t] +
          xs[((size_t)(b * NN) + i) * DM + t];
  float s2 = val, q2 = val * val;
#pragma unroll
  for (int m = 1; m <= 32; m <<= 1) {
    s2 += __shfl_xor(s2, m, 64);
    q2 += __shfl_xor(q2, m, 64);
  }
  if (t < 256 && l == 0) { rs[w] = s2; rq[w] = q2; }
  __syncthreads();
  if (t < 256) {
    float ss = rs[0] + rs[1] + rs[2] + rs[3];
    float qq = rq[0] + rq[1] + rq[2] + rq[3];
    float mu = ss * (1.f / DM);
    float var = qq * (1.f / DM) - mu * mu;
    ys[((size_t)(b * NN) + i) * DM + t] =
        (val - mu) * rsqrtf(var + 1e-5f) * ln_g[t] + ln_b[t];
  }
}

// ---------------- fused FFN: out = gelu(ys@W1+b1)@W2 + b2 + ys -------------
__global__ __launch_bounds__(1024) void k_ffn(const float* __restrict__ ys,
                                              const half_t* __restrict__ W1T,
                                              const float* __restrict__ b1,
                                              const half_t* __restrict__ W2T,
                                              const float* __restrict__ b2,
                                              float* __restrict__ out) {
  __shared__ float sy[2][DM];
  __shared__ float sg[2][1024];
  __shared__ float pp[4][2][256];
  const int t = threadIdx.x;
  const int r0 = blockIdx.x * 2;
  if (t < 512) sy[t >> 8][t & 255] = ys[(size_t)(r0 + (t >> 8)) * DM + (t & 255)];
  __syncthreads();
  float a0 = b1[t], a1 = a0;
#pragma unroll
  for (int k8 = 0; k8 < 32; ++k8) {
    int k = k8 * 8;
    f16x8 wv = *(const f16x8*)(W1T + (size_t)t * 256 + k);
    f32x4 xa0 = *(const f32x4*)(&sy[0][k]);
    f32x4 xb0 = *(const f32x4*)(&sy[0][k + 4]);
    f32x4 xa1 = *(const f32x4*)(&sy[1][k]);
    f32x4 xb1 = *(const f32x4*)(&sy[1][k + 4]);
#pragma unroll
    for (int z = 0; z < 4; ++z) {
      a0 += xa0[z] * (float)wv[z];
      a0 += xb0[z] * (float)wv[z + 4];
      a1 += xa1[z] * (float)wv[z];
      a1 += xb1[z] * (float)wv[z + 4];
    }
  }
  sg[0][t] = 0.5f * a0 * (1.0f + erff(a0 * 0.70710678118654752f));
  sg[1][t] = 0.5f * a1 * (1.0f + erff(a1 * 0.70710678118654752f));
  __syncthreads();
  const int kg = t >> 8, col = t & 255;
  float z0 = 0.f, z1 = 0.f;
#pragma unroll
  for (int k8 = 0; k8 < 32; ++k8) {
    int k = kg * 256 + k8 * 8;
    f16x8 wv = *(const f16x8*)(W2T + (size_t)col * 1024 + k);
    f32x4 ga0 = *(const f32x4*)(&sg[0][k]);
    f32x4 gb0 = *(const f32x4*)(&sg[0][k + 4]);
    f32x4 ga1 = *(const f32x4*)(&sg[1][k]);
    f32x4 gb1 = *(const f32x4*)(&sg[1][k + 4]);
#pragma unroll
    for (int z = 0; z < 4; ++z) {
      z0 += ga0[z] * (float)wv[z];
      z0 += gb0[z] * (float)wv[z + 4];
      z1 += ga1[z] * (float)wv[z];
      z1 += gb1[z] * (float)wv[z + 4];
    }
  }
  pp[kg][0][col] = z0;
  pp[kg][1][col] = z1;
  __syncthreads();
  if (t < 512) {
    int row = t >> 8;
    float r = pp[0][row][col] + pp[1][row][col] + pp[2][row][col] +
              pp[3][row][col] + b2[col] + sy[row][col];
    out[(size_t)(r0 + row) * DM + col] = r;
  }
}

extern "C" void kernel_launch(void* const* d_in, const int* in_sizes, int n_in,
                              void* d_out, int out_size, void* d_ws, size_t ws_size,
                              hipStream_t stream) {
  const float* nodes = (const float*)d_in[0];
  const float* edges = (const float*)d_in[1];
  const float* W     = (const float*)d_in[2];
  const float* bias  = (const float*)d_in[3];
  const float* ln_g  = (const float*)d_in[4];
  const float* ln_b  = (const float*)d_in[5];
  const float* W1    = (const float*)d_in[6];
  const float* b1    = (const float*)d_in[7];
  const float* W2    = (const float*)d_in[8];
  const float* b2    = (const float*)d_in[9];
  float* out = (float*)d_out;

  char* ws = (char*)d_ws;
  float*  xs     = (float*)(ws + 0x000000);   // 512 KB
  float*  nqv    = (float*)(ws + 0x080000);   // 512 KB
  float*  nqvpb  = (float*)(ws + 0x100000);   // 512 KB
  half_t* WT16   = (half_t*)(ws + 0x180000);  // 128 KB
  float*  scores = (float*)(ws + 0x1A0000);   // 4 MB
  float*  ys     = (float*)(ws + 0x5A0000);   // 512 KB
  half_t* W1T16  = (half_t*)(ws + 0x620000);  // 512 KB
  half_t* W2T16  = (half_t*)(ws + 0x6A0000);  // 512 KB

  k_prep<<<1536, 256, 0, stream>>>(W, W1, W2, WT16, W1T16, W2T16);
  k_ln_proj<<<NB * NN / 2, 1024, 0, stream>>>(nodes, WT16, bias, ln_g, ln_b, xs, nqv, nqvpb);
  k_edge_scores<<<NB * NN * (NN / JT), 256, 0, stream>>>(edges, WT16, nqvpb, scores);
  k_attn_out<<<NB * NN, 1024, 0, stream>>>(scores, nqv, WT16, bias, xs, ln_g, ln_b, ys);
  k_ffn<<<NB * NN / 2, 1024, 0, stream>>>(ys, W1T16, b1, W2T16, b2, out);
}